// Round 1
// baseline (598.985 us; speedup 1.0000x reference)
//
#include <hip/hip_runtime.h>
#include <math.h>

#define N 16384
#define D 23
#define S 3
#define P 3
#define K 16
#define JSPLIT 4
#define CHUNK (N / JSPLIT)   // 4096
#define TILE 2048            // points per LDS tile (32 KB as float4)
#define UNR 8

// Sorted ascending insert of (d2, jj) into register arrays vald/vali.
// Caller guarantees d2 < vald[K-1].
#define TOPK_INSERT(vald, vali, d2v, jjv)                          \
  {                                                                \
    bool ck = true;                                                \
    _Pragma("unroll") for (int k = K - 1; k >= 0; --k) {           \
      bool ckm1 = (k > 0) ? ((d2v) < vald[k - 1]) : false;         \
      float nv = ckm1 ? vald[k - 1] : (ck ? (d2v) : vald[k]);      \
      int ni = ckm1 ? vali[k - 1] : (ck ? (jjv) : vali[k]);        \
      vald[k] = nv;                                                \
      vali[k] = ni;                                                \
      ck = ckm1;                                                   \
    }                                                              \
  }

// ---------------------------------------------------------------------------
// Kernel 1: s = x@W_s + b_s, h = x@W_h + b_h, packed as float4 {x,y,z,sq} / {h0,h1,h2,0}
// ---------------------------------------------------------------------------
__global__ __launch_bounds__(64) void prep_kernel(
    const float* __restrict__ x, const float* __restrict__ Ws,
    const float* __restrict__ bs, const float* __restrict__ Wh,
    const float* __restrict__ bh, float4* __restrict__ s4,
    float4* __restrict__ h4) {
  __shared__ float lWs[D * S], lWh[D * P], lbs[S], lbh[P];
  for (int t = threadIdx.x; t < D * S; t += 64) lWs[t] = Ws[t];
  for (int t = threadIdx.x; t < D * P; t += 64) lWh[t] = Wh[t];
  if (threadIdx.x < S) lbs[threadIdx.x] = bs[threadIdx.x];
  if (threadIdx.x < P) lbh[threadIdx.x] = bh[threadIdx.x];
  __syncthreads();

  int i = blockIdx.x * 64 + threadIdx.x;
  float xr[D];
#pragma unroll
  for (int d = 0; d < D; ++d) xr[d] = x[i * D + d];

  float a0 = 0.f, a1 = 0.f, a2 = 0.f;
  float g0 = 0.f, g1 = 0.f, g2 = 0.f;
#pragma unroll
  for (int d = 0; d < D; ++d) {
    float xv = xr[d];
    a0 = fmaf(xv, lWs[d * S + 0], a0);
    a1 = fmaf(xv, lWs[d * S + 1], a1);
    a2 = fmaf(xv, lWs[d * S + 2], a2);
    g0 = fmaf(xv, lWh[d * P + 0], g0);
    g1 = fmaf(xv, lWh[d * P + 1], g1);
    g2 = fmaf(xv, lWh[d * P + 2], g2);
  }
  float s0 = __fadd_rn(a0, lbs[0]);
  float s1 = __fadd_rn(a1, lbs[1]);
  float s2 = __fadd_rn(a2, lbs[2]);
  // sq = s0^2 + s1^2 + s2^2 (fma chain; first fma(s0,s0,0)==rn(s0^2))
  float sq = fmaf(s2, s2, fmaf(s1, s1, __fmul_rn(s0, s0)));
  s4[i] = make_float4(s0, s1, s2, sq);
  h4[i] = make_float4(__fadd_rn(g0, lbh[0]), __fadd_rn(g1, lbh[1]),
                      __fadd_rn(g2, lbh[2]), 0.f);
}

// ---------------------------------------------------------------------------
// Kernel 2: brute-force kNN over one j-chunk per block. One query per lane.
// grid = (N/64) * JSPLIT one-wave blocks.
// ---------------------------------------------------------------------------
__global__ __launch_bounds__(64) void knn_kernel(const float4* __restrict__ s4,
                                                 float* __restrict__ pd2,
                                                 int* __restrict__ pidx) {
  __shared__ float4 tile[TILE];
  int wq = blockIdx.x / JSPLIT;  // query-wave id
  int c = blockIdx.x % JSPLIT;   // j-chunk id
  int i = wq * 64 + threadIdx.x; // this lane's query

  float4 si = s4[i];
  float sqi = si.w;

  float vald[K];
  int vali[K];
#pragma unroll
  for (int k = 0; k < K; ++k) {
    vald[k] = INFINITY;
    vali[k] = 0;
  }

  int jbase = c * CHUNK;
  for (int t0 = 0; t0 < CHUNK; t0 += TILE) {
    for (int t = threadIdx.x; t < TILE; t += 64)
      tile[t] = s4[jbase + t0 + t];
    __syncthreads();

    for (int t = 0; t < TILE; t += UNR) {
      float d2a[UNR];
#pragma unroll
      for (int u = 0; u < UNR; ++u) {
        float4 sj = tile[t + u];  // broadcast read: all lanes same addr
        // mirror reference: dot = fma chain; d2 = (sq_i + sq_j) - 2*dot
        float dot = fmaf(si.z, sj.z, fmaf(si.y, sj.y, __fmul_rn(si.x, sj.x)));
        d2a[u] = __fsub_rn(__fadd_rn(sqi, sj.w), __fmul_rn(2.0f, dot));
      }
#pragma unroll
      for (int u = 0; u < UNR; ++u) {
        float d2 = d2a[u];
        if (d2 < vald[K - 1]) {
          int jj = jbase + t0 + t + u;
          TOPK_INSERT(vald, vali, d2, jj);
        }
      }
    }
    __syncthreads();
  }

#pragma unroll
  for (int k = 0; k < K; ++k) {
    pd2[(size_t)i * (JSPLIT * K) + c * K + k] = vald[k];
    pidx[(size_t)i * (JSPLIT * K) + c * K + k] = vali[k];
  }
}

// ---------------------------------------------------------------------------
// Kernel 3: merge JSPLIT partial top-K lists -> exact top-K; weights, gather h,
// mean/max aggregate -> aggr[N][8] (6 used).
// ---------------------------------------------------------------------------
__global__ __launch_bounds__(64) void merge_kernel(
    const float* __restrict__ pd2, const int* __restrict__ pidx,
    const float4* __restrict__ h4, float* __restrict__ aggr) {
  int i = blockIdx.x * 64 + threadIdx.x;

  float vald[K];
  int vali[K];
#pragma unroll
  for (int k = 0; k < K; ++k) {
    vald[k] = INFINITY;
    vali[k] = 0;
  }
  for (int t = 0; t < JSPLIT * K; ++t) {
    float d2 = pd2[(size_t)i * (JSPLIT * K) + t];
    if (d2 < vald[K - 1]) {
      int jj = pidx[(size_t)i * (JSPLIT * K) + t];
      TOPK_INSERT(vald, vali, d2, jj);
    }
  }

  float m0 = 0.f, m1 = 0.f, m2 = 0.f;
  float x0 = -INFINITY, x1 = -INFINITY, x2 = -INFINITY;
#pragma unroll
  for (int k = 0; k < K; ++k) {
    float d2c = fmaxf(vald[k], 0.f);
    float w = expf(-10.0f * d2c);
    float4 hh = h4[vali[k]];
    float v0 = __fmul_rn(hh.x, w);
    float v1 = __fmul_rn(hh.y, w);
    float v2 = __fmul_rn(hh.z, w);
    m0 += v0; m1 += v1; m2 += v2;
    x0 = fmaxf(x0, v0); x1 = fmaxf(x1, v1); x2 = fmaxf(x2, v2);
  }
  const float inv = 1.0f / (float)K;
  aggr[(size_t)i * 8 + 0] = m0 * inv;
  aggr[(size_t)i * 8 + 1] = m1 * inv;
  aggr[(size_t)i * 8 + 2] = m2 * inv;
  aggr[(size_t)i * 8 + 3] = x0;
  aggr[(size_t)i * 8 + 4] = x1;
  aggr[(size_t)i * 8 + 5] = x2;
}

// ---------------------------------------------------------------------------
// Kernel 4: latent = x@W_o1 + (aggr@W_o2 + b_o2); beta = clip(sigmoid(latent@W_beta+b_beta))
// out[0..N) = beta; out[N + i*D + o] = latent[i][o]
// ---------------------------------------------------------------------------
__global__ __launch_bounds__(64) void out_kernel(
    const float* __restrict__ x, const float* __restrict__ aggr,
    const float* __restrict__ Wo1, const float* __restrict__ Wo2,
    const float* __restrict__ bo2, const float* __restrict__ Wb,
    const float* __restrict__ bb, float* __restrict__ out) {
  __shared__ float lWo1[D * D];      // 529
  __shared__ float lWo2[2 * P * D];  // 138
  __shared__ float lbo2[D], lWb[D];
  __shared__ float lbb;
  for (int t = threadIdx.x; t < D * D; t += 64) lWo1[t] = Wo1[t];
  for (int t = threadIdx.x; t < 2 * P * D; t += 64) lWo2[t] = Wo2[t];
  if (threadIdx.x < D) {
    lbo2[threadIdx.x] = bo2[threadIdx.x];
    lWb[threadIdx.x] = Wb[threadIdx.x];
  }
  if (threadIdx.x == 0) lbb = bb[0];
  __syncthreads();

  int i = blockIdx.x * 64 + threadIdx.x;
  float xr[D];
#pragma unroll
  for (int d = 0; d < D; ++d) xr[d] = x[i * D + d];
  float ag[2 * P];
#pragma unroll
  for (int p = 0; p < 2 * P; ++p) ag[p] = aggr[(size_t)i * 8 + p];

  float z = 0.f;
#pragma unroll
  for (int o = 0; o < D; ++o) {
    float a = 0.f;
#pragma unroll
    for (int d = 0; d < D; ++d) a = fmaf(xr[d], lWo1[d * D + o], a);
    float b2 = 0.f;
#pragma unroll
    for (int p = 0; p < 2 * P; ++p) b2 = fmaf(ag[p], lWo2[p * D + o], b2);
    b2 = __fadd_rn(b2, lbo2[o]);
    float lat = __fadd_rn(a, b2);
    out[(size_t)N + (size_t)i * D + o] = lat;
    z = fmaf(lat, lWb[o], z);
  }
  z = __fadd_rn(z, lbb);
  float beta = 1.0f / (1.0f + expf(-z));
  beta = fminf(fmaxf(beta, 1e-6f), 1.0f - 1e-6f);
  out[i] = beta;
}

// ---------------------------------------------------------------------------
extern "C" void kernel_launch(void* const* d_in, const int* in_sizes, int n_in,
                              void* d_out, int out_size, void* d_ws,
                              size_t ws_size, hipStream_t stream) {
  const float* x = (const float*)d_in[0];
  const float* Ws = (const float*)d_in[1];
  const float* bs = (const float*)d_in[2];
  const float* Wh = (const float*)d_in[3];
  const float* bh = (const float*)d_in[4];
  const float* Wo1 = (const float*)d_in[5];
  const float* Wo2 = (const float*)d_in[6];
  const float* bo2 = (const float*)d_in[7];
  const float* Wb = (const float*)d_in[8];
  const float* bb = (const float*)d_in[9];
  float* out = (float*)d_out;
  float* ws = (float*)d_ws;

  // workspace layout (floats): s4[N*4] | h4[N*4] | aggr[N*8] | pd2[N*64] | pidx[N*64]
  float* s4 = ws;
  float* h4 = ws + (size_t)N * 4;
  float* aggr = ws + (size_t)N * 8;
  float* pd2 = ws + (size_t)N * 16;
  int* pidx = (int*)(ws + (size_t)N * 16 + (size_t)N * 64);

  prep_kernel<<<N / 64, 64, 0, stream>>>(x, Ws, bs, Wh, bh, (float4*)s4,
                                         (float4*)h4);
  knn_kernel<<<(N / 64) * JSPLIT, 64, 0, stream>>>((const float4*)s4, pd2,
                                                   pidx);
  merge_kernel<<<N / 64, 64, 0, stream>>>(pd2, pidx, (const float4*)h4, aggr);
  out_kernel<<<N / 64, 64, 0, stream>>>(x, aggr, Wo1, Wo2, bo2, Wb, bb, out);
}